// Round 16
// baseline (356.629 us; speedup 1.0000x reference)
//
#include <hip/hip_runtime.h>
#include <math.h>

namespace {

constexpr int C_ = 3, T_ = 3000, F_ = 103, NB_ = 6;
constexpr int TT = 20;                       // rows per tile (4 waves x 5 rows)
constexpr int NT = 3;                        // tiles per block
constexpr int RPW = 5;                       // rows per wave
constexpr int BS[NB_]  = {1, 10, 20, 30, 40, 61};
constexpr int BNB[NB_] = {10, 11, 11, 11, 22, 16};
constexpr int WSTART[NB_] = {0, 5, 10, 15, 20, 30};
constexpr int WCNT[NB_]   = {6, 6, 6, 6, 11, 9};
constexpr int WOFF[NB_]   = {0, 6, 12, 18, 24, 35};
constexpr int WROW = 44;
constexpr int WTOTU = 18 * WROW;             // 792 packed u32 weights
constexpr int SREG = 780;                    // union region words/wave: spec 600 | enh 780
constexpr int PLANE = T_ * F_;               // 309000
constexpr int WELE = RPW * F_;               // 515 elements per wave per tile

__device__ __forceinline__ float softplus_(float x) {
  return fmaxf(x, 0.0f) + log1pf(expf(-fabsf(x)));
}
__device__ __forceinline__ float sigmoid_(float z) {
  return 1.0f / (1.0f + __expf(-z));
}
__device__ __forceinline__ float gelu_(float x) {
  return x * sigmoid_(1.595769122f * x * (1.0f + 0.044715f * x * x));
}
__device__ __forceinline__ unsigned bf16_rne_(float x) {
  unsigned b = __float_as_uint(x);
  b += 0x7FFFu + ((b >> 16) & 1u);
  return b >> 16;
}
__device__ __forceinline__ float bl_(unsigned u) { return __uint_as_float(u << 16); }
__device__ __forceinline__ float bh_(unsigned u) { return __uint_as_float(u & 0xffff0000u); }
// wave-local LDS fence: orders cross-lane LDS handoffs within one wave64
__device__ __forceinline__ void wfence_() {
  asm volatile("s_waitcnt lgkmcnt(0)" ::: "memory");
  __builtin_amdgcn_wave_barrier();
}

// ---- pre-kernel: global-parity packed bf16 gaussian bank + folded proj/BN -----
__global__ __launch_bounds__(128)
void prep_kernel(const float* __restrict__ centers,
                 const float* __restrict__ widths,
                 const float* __restrict__ gains,
                 const float* __restrict__ proj_w,
                 const float* __restrict__ proj_b,
                 const float* __restrict__ bn_gamma,
                 const float* __restrict__ bn_beta,
                 const float* __restrict__ bn_mean,
                 const float* __restrict__ bn_var,
                 float* __restrict__ ws)
{
  unsigned* wsU = (unsigned*)ws;
  const int q = threadIdx.x;
  if (q < 108) {
    int i = q / 18;
    int p = q - i * 18;                       // c*6+n
    int s = BS[i], nb = BNB[i];
    float mu = softplus_(centers[q]) + (float)s;
    mu = fminf(fmaxf(mu, (float)s), (float)(s + nb - 1));
    float sd = softplus_(widths[q]) + 0.001f;
    sd = fminf(fmaxf(sd, 0.5f), 2.0f * (float)nb / 6.0f);
    float sum = 0.0f;
    for (int f = 0; f < nb; ++f) {
      float d = ((float)f - mu) / sd;
      sum += __expf(-0.5f * d * d);
    }
    float sc = gains[q] / (sum + 1e-6f);
    float wtmp[22];
    for (int f = 0; f < nb; ++f) {
      float d = ((float)f - mu) / sd;
      wtmp[f] = sc * __expf(-0.5f * d * d);
    }
    for (int e = 0; e < WCNT[i]; ++e) {
      int flo = 2 * (WSTART[i] + e) - s;
      int fhi = flo + 1;
      unsigned lo = (flo >= 0 && flo < nb) ? bf16_rne_(wtmp[flo]) : 0u;
      unsigned hi = (fhi >= 0 && fhi < nb) ? bf16_rne_(wtmp[fhi]) : 0u;
      wsU[p * WROW + WOFF[i] + e] = lo | (hi << 16);
    }
  } else if (q < 117) {
    int k = q - 108, d = k / 3;
    float sc = bn_gamma[d] / sqrtf(bn_var[d] + 1e-5f);
    ws[WTOTU + k] = proj_w[k] * sc;
  } else if (q < 120) {
    int d = q - 117;
    float sc = bn_gamma[d] / sqrtf(bn_var[d] + 1e-5f);
    ws[WTOTU + 9 + d] = (proj_b[d] - bn_mean[d]) * sc + bn_beta[d];
  }
}

// ---- main kernel: barrier-free wave-synchronous pipeline ----------------------
// Wave w owns rows tt = 5w..5w+4 of each tile; phases fence wave-locally only.
__global__ __launch_bounds__(256, 6)
void sleepband_kernel(const float* __restrict__ spec,
                      const float* __restrict__ ws,
                      const float* __restrict__ align_w,
                      const float* __restrict__ align_b,
                      const float* __restrict__ fc1_w,
                      const float* __restrict__ fc1_b,
                      const float* __restrict__ fc2_w,
                      const float* __restrict__ fc2_b,
                      const float* __restrict__ band_gain,
                      const float* __restrict__ gate_w,
                      const float* __restrict__ gate_b,
                      float* __restrict__ out)
{
  __shared__ unsigned sW4[4][SREG];      // per-wave union: spec [ttl][c][40] | enh [c][ttl][52]
  __shared__ unsigned sWu[WTOTU];        // packed bf16 weight pairs (block-shared, RO)
  __shared__ float sBand[TT][109];       // row = 5w+ttl; odd stride -> conflict-free
  __shared__ float sAw[54], sAb[18], sF1[108], sF1b[6], sF2[108], sF2b[18],
                   sBg[6], sGw[9], sGb[3], sPw[9], sPb[3];

  const int tid  = threadIdx.x;
  const int w    = tid >> 6;             // wave id 0..3
  const int lane = tid & 63;
  const int b    = blockIdx.y;
  const float* specB = spec + (size_t)b * C_ * PLANE;
  float* outBase = out + (size_t)b * C_ * PLANE;
  const unsigned* wsU = (const unsigned*)ws;
  unsigned* reg = &sW4[w][0];

  // ---- one-time prologue (block-wide; the ONLY s_barrier) ----
  for (int k = tid; k < WTOTU; k += 256) sWu[k] = wsU[k];
  if (tid < 54)  sAw[tid]  = align_w[tid];
  if (tid < 18)  sAb[tid]  = align_b[tid];
  if (tid < 108) sF1[tid]  = fc1_w[tid];
  if (tid < 6)   sF1b[tid] = fc1_b[tid];
  if (tid < 108) sF2[tid]  = fc2_w[tid];
  if (tid < 18)  sF2b[tid] = fc2_b[tid];
  if (tid < 6)   sBg[tid]  = band_gain[tid];
  if (tid < 9)   sGw[tid]  = gate_w[tid];
  if (tid < 3)   sGb[tid]  = gate_b[tid];
  if (tid < 9)   sPw[tid]  = ws[WTOTU + tid];
  if (tid < 3)   sPb[tid]  = ws[WTOTU + 9 + tid];
  __syncthreads();

  float gw[9], pw[9], gb3[3], pb3[3];
  #pragma unroll
  for (int k = 0; k < 9; ++k) { gw[k] = sGw[k]; pw[k] = sPw[k]; }
  #pragma unroll
  for (int k = 0; k < 3; ++k) { gb3[k] = sGb[k]; pb3[k] = sPb[k]; }

  for (int tile = 0; tile < NT; ++tile) {
    const int t0 = (blockIdx.x * NT + tile) * TT;
    const int tw = t0 + w * RPW;               // wave's first global t

    // ---- STAGE (wave-local): spec rows -> packed bf16 [ttl][c][40] ----
    for (int li = lane; li < RPW * C_ * 40; li += 64) {
      int ttl = li / 120;
      int rem = li - ttl * 120;
      int c   = rem / 40;
      int wd  = rem - c * 40;
      unsigned v = 0u;
      if (wd < 39) {
        const float* gr = specB + (size_t)c * PLANE + (size_t)(tw + ttl) * F_;
        v = bf16_rne_(gr[2 * wd]) | (bf16_rne_(gr[2 * wd + 1]) << 16);
      }
      reg[li] = v;
    }
    wfence_();

    // ---- Phase A: filt, n-pair tasks (45 per wave) ----
    if (lane < 45) {
      const int g   = lane / RPW;          // c*3 + np
      const int ttl = lane - g * RPW;
      const int c   = g / 3;
      const int np  = g - c * 3;
      const int n0  = 2 * np;
      const int row = w * RPW + ttl;
      const unsigned* srow = reg + (ttl * 3 + c) * 40;
      const unsigned* w0 = &sWu[(c * 6 + n0) * WROW];
      const unsigned* w1 = w0 + WROW;
      #pragma unroll
      for (int i = 0; i < NB_; ++i) {
        float a0 = 0.0f, a1 = 0.0f;
        #pragma unroll
        for (int e = 0; e < WCNT[i]; ++e) {
          unsigned su = srow[WSTART[i] + e];
          float s0 = bl_(su), s1 = bh_(su);
          unsigned u0 = w0[WOFF[i] + e], u1 = w1[WOFF[i] + e];
          a0 += s0 * bl_(u0); a0 += s1 * bh_(u0);
          a1 += s0 * bl_(u1); a1 += s1 * bh_(u1);
        }
        sBand[row][(i * 3 + c) * 6 + n0]     = a0;
        sBand[row][(i * 3 + c) * 6 + n0 + 1] = a1;
      }
    }
    wfence_();

    // ---- Phase B: align + MLP + softmax + scale (30 tasks per wave) ----
    if (lane < 6 * RPW) {
      const int n   = lane / RPW;
      const int ttl = lane - n * RPW;
      const int row = w * RPW + ttl;
      float al[18];
      #pragma unroll
      for (int i = 0; i < 6; ++i) {
        float f0 = sBand[row][(i * 3 + 0) * 6 + n];
        float f1 = sBand[row][(i * 3 + 1) * 6 + n];
        float f2 = sBand[row][(i * 3 + 2) * 6 + n];
        #pragma unroll
        for (int d = 0; d < 3; ++d)
          al[i * 3 + d] = sAw[i * 9 + d * 3 + 0] * f0 + sAw[i * 9 + d * 3 + 1] * f1 +
                          sAw[i * 9 + d * 3 + 2] * f2 + sAb[i * 3 + d];
      }
      float h[6];
      #pragma unroll
      for (int o = 0; o < 6; ++o) {
        float acc = sF1b[o];
        #pragma unroll
        for (int k = 0; k < 18; ++k) acc += sF1[o * 18 + k] * al[k];
        h[o] = gelu_(acc);
      }
      float at[18];
      #pragma unroll
      for (int k = 0; k < 18; ++k) {
        float acc = sF2b[k];
        #pragma unroll
        for (int o = 0; o < 6; ++o) acc += sF2[k * 6 + o] * h[o];
        at[k] = acc;
      }
      #pragma unroll
      for (int c = 0; c < 3; ++c) {
        float m = at[c];
        #pragma unroll
        for (int i = 1; i < 6; ++i) m = fmaxf(m, at[i * 3 + c]);
        float e[6], ssum = 0.0f;
        #pragma unroll
        for (int i = 0; i < 6; ++i) { e[i] = __expf(at[i * 3 + c] - m); ssum += e[i]; }
        float inv = 1.0f / ssum;
        #pragma unroll
        for (int i = 0; i < 6; ++i)
          sBand[row][(i * 3 + c) * 6 + n] = al[i * 3 + c] * (e[i] * inv) * sBg[i];
      }
    }
    wfence_();

    // ---- Phase B2: upsample -> packed bf16 enh [c][ttl][52] (15 tasks/wave) ----
    if (lane < C_ * RPW) {
      const int c   = lane / RPW;
      const int ttl = lane - c * RPW;
      const int row = w * RPW + ttl;
      float bnd[36];
      #pragma unroll
      for (int i = 0; i < 6; ++i)
        #pragma unroll
        for (int n = 0; n < 6; ++n)
          bnd[i * 6 + n] = sBand[row][(i * 3 + c) * 6 + n];
      unsigned* rowU = reg + c * (RPW * 52) + ttl * 52;
      float pend = 0.0f;
      float carry = 0.0f;
      #pragma unroll
      for (int i = 0; i < NB_; ++i) {
        #pragma unroll
        for (int j = 0; j < BNB[i]; ++j) {
          const int f = BS[i] + j;
          float src = ((float)j + 0.5f) * 6.0f / (float)BNB[i] - 0.5f;
          src = src > 0.0f ? src : 0.0f;
          int   x0 = (int)src;
          int   x1 = (x0 < 5) ? x0 + 1 : 5;
          float wl = src - (float)x0;
          float v  = bnd[i * 6 + x0] * (1.0f - wl) + bnd[i * 6 + x1] * wl;
          if (j == 0) v += carry;
          if (i < NB_ - 1 && j == BNB[i] - 1) {
            carry = v;
          } else {
            if (f & 1) rowU[f >> 1] = bf16_rne_(pend) | (bf16_rne_(v) << 16);
            else       pend = v;
          }
        }
      }
      rowU[38] = bf16_rne_(pend);
      #pragma unroll
      for (int wdz = 39; wdz < 52; ++wdz) rowU[wdz] = 0u;
    }
    wfence_();

    // ---- FINAL (wave-local flat range [515w, 515w+515) within tile) ----
    const float* sp0 = specB + (size_t)t0 * F_;
    float* outB = outBase + (size_t)t0 * F_;
    const int wbeg = WELE * w, wend = wbeg + WELE;
    const int astart = (wbeg + 3) & ~3, aend = wend & ~3;

    auto finElem = [&](int idx) {
      const int tt  = idx / F_;
      const int f   = idx - tt * F_;
      const int ttl = tt - w * RPW;
      const int wd  = ttl * 52 + (f >> 1);
      const bool hi = (f & 1);
      const unsigned ua = reg[wd];
      const unsigned ub = reg[260 + wd];
      const unsigned uc = reg[520 + wd];
      float e0 = hi ? bh_(ua) : bl_(ua);
      float e1 = hi ? bh_(ub) : bl_(ub);
      float e2 = hi ? bh_(uc) : bl_(uc);
      float sv0 = sp0[idx], sv1 = sp0[PLANE + idx], sv2 = sp0[2 * PLANE + idx];
      float r0 = e0 - sv0, r1 = e1 - sv1, r2 = e2 - sv2;
      float e20 = sv0 + sigmoid_(gw[0] * r0 + gw[1] * r1 + gw[2] * r2 + gb3[0]) * r0;
      float e21 = sv1 + sigmoid_(gw[3] * r0 + gw[4] * r1 + gw[5] * r2 + gb3[1]) * r1;
      float e22 = sv2 + sigmoid_(gw[6] * r0 + gw[7] * r1 + gw[8] * r2 + gb3[2]) * r2;
      outB[idx] = gelu_(pw[0] * e20 + pw[1] * e21 + pw[2] * e22 + pb3[0]);
      outB[PLANE + idx] = gelu_(pw[3] * e20 + pw[4] * e21 + pw[5] * e22 + pb3[1]);
      outB[2 * PLANE + idx] = gelu_(pw[6] * e20 + pw[7] * e21 + pw[8] * e22 + pb3[2]);
    };

    if (lane < astart - wbeg) finElem(wbeg + lane);        // lead scalars (<=3)
    if (lane < wend - aend)   finElem(aend + lane);        // tail scalars (<=3)

    for (int e = astart + 4 * lane; e < aend; e += 256) {  // 128 aligned chunks
      const float4 sA = *(const float4*)(sp0 + e);
      const float4 sB = *(const float4*)(sp0 + PLANE + e);
      const float4 sC = *(const float4*)(sp0 + 2 * PLANE + e);
      float4 oA, oB, oC;
      const float* sAp = (const float*)&sA; const float* sBp = (const float*)&sB;
      const float* sCp = (const float*)&sC;
      float* oAp = (float*)&oA; float* oBp = (float*)&oB; float* oCp = (float*)&oC;
      #pragma unroll
      for (int j = 0; j < 4; ++j) {
        const int idx = e + j;
        const int tt  = idx / F_;
        const int f   = idx - tt * F_;
        const int ttl = tt - w * RPW;
        const int wd  = ttl * 52 + (f >> 1);
        const bool hi = (f & 1);
        const unsigned ua = reg[wd];
        const unsigned ub = reg[260 + wd];
        const unsigned uc = reg[520 + wd];
        float e0 = hi ? bh_(ua) : bl_(ua);
        float e1 = hi ? bh_(ub) : bl_(ub);
        float e2 = hi ? bh_(uc) : bl_(uc);
        float sv0 = sAp[j], sv1 = sBp[j], sv2 = sCp[j];
        float r0 = e0 - sv0, r1 = e1 - sv1, r2 = e2 - sv2;
        float e20 = sv0 + sigmoid_(gw[0] * r0 + gw[1] * r1 + gw[2] * r2 + gb3[0]) * r0;
        float e21 = sv1 + sigmoid_(gw[3] * r0 + gw[4] * r1 + gw[5] * r2 + gb3[1]) * r1;
        float e22 = sv2 + sigmoid_(gw[6] * r0 + gw[7] * r1 + gw[8] * r2 + gb3[2]) * r2;
        oAp[j] = gelu_(pw[0] * e20 + pw[1] * e21 + pw[2] * e22 + pb3[0]);
        oBp[j] = gelu_(pw[3] * e20 + pw[4] * e21 + pw[5] * e22 + pb3[1]);
        oCp[j] = gelu_(pw[6] * e20 + pw[7] * e21 + pw[8] * e22 + pb3[2]);
      }
      *(float4*)(outB + e) = oA;
      *(float4*)(outB + PLANE + e) = oB;
      *(float4*)(outB + 2 * PLANE + e) = oC;
    }
    wfence_();   // protect reg (enh) before next tile's stage overwrites it
  }
}

} // namespace

extern "C" void kernel_launch(void* const* d_in, const int* in_sizes, int n_in,
                              void* d_out, int out_size, void* d_ws, size_t ws_size,
                              hipStream_t stream) {
  (void)n_in; (void)out_size; (void)ws_size;
  const int B = in_sizes[0] / (C_ * T_ * F_);   // 64
  float* ws = (float*)d_ws;                     // 792 u32 + 12 f32
  prep_kernel<<<1, 128, 0, stream>>>(
      (const float*)d_in[1],  (const float*)d_in[2],  (const float*)d_in[3],
      (const float*)d_in[13], (const float*)d_in[14], (const float*)d_in[15],
      (const float*)d_in[16], (const float*)d_in[17], (const float*)d_in[18], ws);
  dim3 grid(T_ / (TT * NT), B);                 // (50, 64)
  sleepband_kernel<<<grid, 256, 0, stream>>>(
      (const float*)d_in[0],  ws,
      (const float*)d_in[4],  (const float*)d_in[5],
      (const float*)d_in[6],  (const float*)d_in[7],  (const float*)d_in[8],
      (const float*)d_in[9],  (const float*)d_in[10], (const float*)d_in[11],
      (const float*)d_in[12], (float*)d_out);
}

// Round 17
// 285.300 us; speedup vs baseline: 1.2500x; 1.2500x over previous
//
#include <hip/hip_runtime.h>
#include <math.h>

namespace {

constexpr int C_ = 3, T_ = 3000, F_ = 103, NB_ = 6;
constexpr int BS[NB_]  = {1, 10, 20, 30, 40, 61};
constexpr int BNB[NB_] = {10, 11, 11, 11, 22, 16};
constexpr int WSTART[NB_] = {0, 5, 10, 15, 20, 30};
constexpr int WCNT[NB_]   = {6, 6, 6, 6, 11, 9};
constexpr int WOFF[NB_]   = {0, 6, 12, 18, 24, 35};
constexpr int WROW  = 44;
constexpr int WTOTU = 18 * WROW;            // 792 packed u32 weights
constexpr int TAPOFF  = 804;                // u32 idx: taps (103 x 5)
constexpr int BANDOFF = 2048;               // u32 idx: band tensor
constexpr int BROW = 54;                    // u32 words per band row (108 bf16)
constexpr int PLANE = T_ * F_;
// kernel1 (band)
constexpr int TT1 = 32;
constexpr int SROWP = 121;                  // padded spec row stride (u32/tt)
constexpr int BROWP = 55;                   // padded band LDS row stride (u32)
// kernel2 (out)
constexpr int TT2 = 20;
// fused fallback (R13)
constexpr int TTF = 20, NTF = 3;
constexpr int SPW = 39, SPECW = C_ * TTF * SPW, ERS = 52, EPL = TTF * ERS,
              POOLU = 3 * EPL;

__device__ __forceinline__ float softplus_(float x) {
  return fmaxf(x, 0.0f) + log1pf(expf(-fabsf(x)));
}
__device__ __forceinline__ float sigmoid_(float z) {
  return 1.0f / (1.0f + __expf(-z));
}
__device__ __forceinline__ float gelu_(float x) {
  return x * sigmoid_(1.595769122f * x * (1.0f + 0.044715f * x * x));
}
__device__ __forceinline__ unsigned bf16_rne_(float x) {
  unsigned b = __float_as_uint(x);
  b += 0x7FFFu + ((b >> 16) & 1u);
  return b >> 16;
}
__device__ __forceinline__ float bl_(unsigned u) { return __uint_as_float(u << 16); }
__device__ __forceinline__ float bh_(unsigned u) { return __uint_as_float(u & 0xffff0000u); }
__device__ __forceinline__ float b16_(unsigned short u) {
  return __uint_as_float((unsigned)u << 16);
}

// ---- prep: packed bf16 gaussian bank + folded proj/BN + tap table -> d_ws -----
__global__ __launch_bounds__(256)
void prep_kernel(const float* __restrict__ centers,
                 const float* __restrict__ widths,
                 const float* __restrict__ gains,
                 const float* __restrict__ proj_w,
                 const float* __restrict__ proj_b,
                 const float* __restrict__ bn_gamma,
                 const float* __restrict__ bn_beta,
                 const float* __restrict__ bn_mean,
                 const float* __restrict__ bn_var,
                 float* __restrict__ ws)
{
  unsigned* wsU = (unsigned*)ws;
  const int q = threadIdx.x;
  if (q < 108) {
    int i = q / 18;
    int p = q - i * 18;                       // c*6+n
    int s = BS[i], nb = BNB[i];
    float mu = softplus_(centers[q]) + (float)s;
    mu = fminf(fmaxf(mu, (float)s), (float)(s + nb - 1));
    float sd = softplus_(widths[q]) + 0.001f;
    sd = fminf(fmaxf(sd, 0.5f), 2.0f * (float)nb / 6.0f);
    float sum = 0.0f;
    for (int f = 0; f < nb; ++f) {
      float d = ((float)f - mu) / sd;
      sum += __expf(-0.5f * d * d);
    }
    float sc = gains[q] / (sum + 1e-6f);
    float wtmp[22];
    for (int f = 0; f < nb; ++f) {
      float d = ((float)f - mu) / sd;
      wtmp[f] = sc * __expf(-0.5f * d * d);
    }
    for (int e = 0; e < WCNT[i]; ++e) {
      int flo = 2 * (WSTART[i] + e) - s;
      int fhi = flo + 1;
      unsigned lo = (flo >= 0 && flo < nb) ? bf16_rne_(wtmp[flo]) : 0u;
      unsigned hi = (fhi >= 0 && fhi < nb) ? bf16_rne_(wtmp[fhi]) : 0u;
      wsU[p * WROW + WOFF[i] + e] = lo | (hi << 16);
    }
  } else if (q < 117) {
    int k = q - 108, d = k / 3;
    float sc = bn_gamma[d] / sqrtf(bn_var[d] + 1e-5f);
    ws[WTOTU + k] = proj_w[k] * sc;
  } else if (q < 120) {
    int d = q - 117;
    float sc = bn_gamma[d] / sqrtf(bn_var[d] + 1e-5f);
    ws[WTOTU + 9 + d] = (proj_b[d] - bn_mean[d]) * sc + bn_beta[d];
  } else if (q >= 128 && q < 128 + F_) {
    const int f = q - 128;
    unsigned cols = 0;
    float w4[4] = {0.f, 0.f, 0.f, 0.f};
    int slot = 0;
    #pragma unroll
    for (int i = 0; i < NB_; ++i) {
      if (f >= BS[i] && f < BS[i] + BNB[i]) {
        int j = f - BS[i];
        float src = ((float)j + 0.5f) * 6.0f / (float)BNB[i] - 0.5f;
        src = src > 0.0f ? src : 0.0f;
        int x0 = (int)src;
        int x1 = (x0 < 5) ? x0 + 1 : 5;
        float wl = src - (float)x0;
        cols |= ((unsigned)(i * 18 + x0) << (16 * slot))
              | ((unsigned)(i * 18 + x1) << (16 * slot + 8));
        w4[2 * slot] = 1.0f - wl;
        w4[2 * slot + 1] = wl;
        ++slot;
      }
    }
    wsU[TAPOFF + f * 5] = cols;
    #pragma unroll
    for (int k = 0; k < 4; ++k) ws[TAPOFF + f * 5 + 1 + k] = w4[k];
  }
}

// ---- kernel1: per-(t,n) fused A+B in registers -> band[b][t][54] (bf16x2) -----
__global__ __launch_bounds__(192)
void band_kernel(const float* __restrict__ spec,
                 const float* __restrict__ ws,
                 const float* __restrict__ align_w,
                 const float* __restrict__ align_b,
                 const float* __restrict__ fc1_w,
                 const float* __restrict__ fc1_b,
                 const float* __restrict__ fc2_w,
                 const float* __restrict__ fc2_b,
                 const float* __restrict__ band_gain,
                 unsigned* __restrict__ band)
{
  __shared__ unsigned specP[TT1 * SROWP];   // packed bf16 spec, padded rows
  __shared__ unsigned bandL[TT1 * BROWP];   // packed bf16 band, padded rows
  __shared__ unsigned sWu[WTOTU];
  __shared__ float sAw[54], sAb[18], sF1[108], sF1b[6], sF2[108], sF2b[18], sBg[6];

  const int tid = threadIdx.x;
  const int b   = blockIdx.y;
  const int t0  = blockIdx.x * TT1;
  const float* specB = spec + (size_t)b * C_ * PLANE;
  const unsigned* wsU = (const unsigned*)ws;

  for (int k = tid; k < WTOTU; k += 192) sWu[k] = wsU[k];
  if (tid < 54)  sAw[tid]  = align_w[tid];
  if (tid < 18)  sAb[tid]  = align_b[tid];
  if (tid < 108) sF1[tid]  = fc1_w[tid];
  if (tid < 6)   sF1b[tid] = fc1_b[tid];
  if (tid < 108) sF2[tid]  = fc2_w[tid];
  if (tid < 18)  sF2b[tid] = fc2_b[tid];
  if (tid < 6)   sBg[tid]  = band_gain[tid];

  // ---- stage spec rows (packed bf16 pairs, f 0..77) ----
  for (int li = tid; li < TT1 * 120; li += 192) {
    int tt  = li / 120;
    int rem = li - tt * 120;
    int c   = rem / 40;
    int wd  = rem - c * 40;
    unsigned v = 0u;
    if (wd < 39 && t0 + tt < T_) {
      const float* gr = specB + (size_t)c * PLANE + (size_t)(t0 + tt) * F_;
      v = bf16_rne_(gr[2 * wd]) | (bf16_rne_(gr[2 * wd + 1]) << 16);
    }
    specP[tt * SROWP + c * 40 + wd] = v;
  }
  __syncthreads();

  // ---- fused A+B per (tt, n): 192 lanes fully active ----
  {
    const int tt = tid / 6;
    const int n  = tid - tt * 6;
    if (t0 + tt < T_) {
      float filt[NB_][3];
      #pragma unroll
      for (int i = 0; i < NB_; ++i) {
        #pragma unroll
        for (int c = 0; c < 3; ++c) {
          const unsigned* srow = &specP[tt * SROWP + c * 40];
          const unsigned* wr = &sWu[(c * 6 + n) * WROW];
          float a = 0.0f;
          #pragma unroll
          for (int e = 0; e < WCNT[i]; ++e) {
            unsigned su = srow[WSTART[i] + e];
            unsigned wu = wr[WOFF[i] + e];
            a += bl_(su) * bl_(wu);
            a += bh_(su) * bh_(wu);
          }
          filt[i][c] = a;
        }
      }
      float al[18];
      #pragma unroll
      for (int i = 0; i < 6; ++i)
        #pragma unroll
        for (int d = 0; d < 3; ++d)
          al[i * 3 + d] = sAw[i * 9 + d * 3 + 0] * filt[i][0] +
                          sAw[i * 9 + d * 3 + 1] * filt[i][1] +
                          sAw[i * 9 + d * 3 + 2] * filt[i][2] + sAb[i * 3 + d];
      float h[6];
      #pragma unroll
      for (int o = 0; o < 6; ++o) {
        float acc = sF1b[o];
        #pragma unroll
        for (int k = 0; k < 18; ++k) acc += sF1[o * 18 + k] * al[k];
        h[o] = gelu_(acc);
      }
      unsigned short* bu = (unsigned short*)bandL;
      #pragma unroll
      for (int c = 0; c < 3; ++c) {
        float a[6];
        #pragma unroll
        for (int i = 0; i < 6; ++i) {
          float x = sF2b[i * 3 + c];
          #pragma unroll
          for (int o = 0; o < 6; ++o) x += sF2[(i * 3 + c) * 6 + o] * h[o];
          a[i] = x;
        }
        float m = a[0];
        #pragma unroll
        for (int i = 1; i < 6; ++i) m = fmaxf(m, a[i]);
        float e[6], ssum = 0.0f;
        #pragma unroll
        for (int i = 0; i < 6; ++i) { e[i] = __expf(a[i] - m); ssum += e[i]; }
        float inv = 1.0f / ssum;
        #pragma unroll
        for (int i = 0; i < 6; ++i) {
          float v = al[i * 3 + c] * (e[i] * inv) * sBg[i];
          bu[tt * (2 * BROWP) + i * 18 + c * 6 + n] = (unsigned short)bf16_rne_(v);
        }
      }
    }
  }
  __syncthreads();

  // ---- coalesced band write: [b][t][54] u32 ----
  for (int li = tid; li < TT1 * BROW; li += 192) {
    int tt = li / BROW;
    int wd = li - tt * BROW;
    if (t0 + tt < T_)
      band[((size_t)b * T_ + (t0 + tt)) * BROW + wd] = bandL[tt * BROWP + wd];
  }
}

// ---- kernel2: streaming tap-gather final ---------------------------------------
__global__ __launch_bounds__(256)
void out_kernel(const float* __restrict__ spec,
                const float* __restrict__ ws,
                const unsigned* __restrict__ band,
                const float* __restrict__ gate_w,
                const float* __restrict__ gate_b,
                float* __restrict__ out)
{
  __shared__ unsigned bandL[TT2 * BROWP];   // padded rows (u16 view [tt][110])
  __shared__ unsigned sTap[F_ * 5];
  __shared__ float sGw[9], sGb[3], sPw[9], sPb[3];

  const int tid = threadIdx.x;
  const int b   = blockIdx.y;
  const int t0  = blockIdx.x * TT2;
  const unsigned* wsU = (const unsigned*)ws;

  for (int li = tid; li < TT2 * BROW; li += 256) {
    int tt = li / BROW;
    int wd = li - tt * BROW;
    bandL[tt * BROWP + wd] = band[((size_t)b * T_ + (t0 + tt)) * BROW + wd];
  }
  for (int k = tid; k < F_ * 5; k += 256) sTap[k] = wsU[TAPOFF + k];
  if (tid < 9) sGw[tid] = gate_w[tid];
  if (tid < 3) sGb[tid] = gate_b[tid];
  if (tid < 9) sPw[tid] = ws[WTOTU + tid];
  if (tid < 3) sPb[tid] = ws[WTOTU + 9 + tid];
  __syncthreads();

  float gw[9], pw[9], gb3[3], pb3[3];
  #pragma unroll
  for (int k = 0; k < 9; ++k) { gw[k] = sGw[k]; pw[k] = sPw[k]; }
  #pragma unroll
  for (int k = 0; k < 3; ++k) { gb3[k] = sGb[k]; pb3[k] = sPb[k]; }

  const unsigned short* bu = (const unsigned short*)bandL;
  const float* sp0 = spec + (size_t)b * C_ * PLANE + (size_t)t0 * F_;
  float* outB = out + (size_t)b * C_ * PLANE + (size_t)t0 * F_;

  for (int e4 = tid; e4 < (TT2 * F_) / 4; e4 += 256) {
    const int e = e4 * 4;
    const float4 sA = *(const float4*)(sp0 + e);
    const float4 sB = *(const float4*)(sp0 + PLANE + e);
    const float4 sC = *(const float4*)(sp0 + 2 * PLANE + e);
    float4 oA, oB, oC;
    const float* sAp = (const float*)&sA; const float* sBp = (const float*)&sB;
    const float* sCp = (const float*)&sC;
    float* oAp = (float*)&oA; float* oBp = (float*)&oB; float* oCp = (float*)&oC;
    #pragma unroll
    for (int j = 0; j < 4; ++j) {
      const int idx = e + j;
      const int tt  = idx / F_;
      const int f   = idx - tt * F_;
      const unsigned cp = sTap[f * 5];
      const float wa0 = __uint_as_float(sTap[f * 5 + 1]);
      const float wb0 = __uint_as_float(sTap[f * 5 + 2]);
      const float wa1 = __uint_as_float(sTap[f * 5 + 3]);
      const float wb1 = __uint_as_float(sTap[f * 5 + 4]);
      const int base = tt * (2 * BROWP);
      const int ca0 = cp & 0xffu, cb0 = (cp >> 8) & 0xffu;
      const int ca1 = (cp >> 16) & 0xffu, cb1 = cp >> 24;
      float e0 = wa0 * b16_(bu[base + ca0])      + wb0 * b16_(bu[base + cb0])
               + wa1 * b16_(bu[base + ca1])      + wb1 * b16_(bu[base + cb1]);
      float e1 = wa0 * b16_(bu[base + ca0 + 6])  + wb0 * b16_(bu[base + cb0 + 6])
               + wa1 * b16_(bu[base + ca1 + 6])  + wb1 * b16_(bu[base + cb1 + 6]);
      float e2 = wa0 * b16_(bu[base + ca0 + 12]) + wb0 * b16_(bu[base + cb0 + 12])
               + wa1 * b16_(bu[base + ca1 + 12]) + wb1 * b16_(bu[base + cb1 + 12]);
      float sv0 = sAp[j], sv1 = sBp[j], sv2 = sCp[j];
      float r0 = e0 - sv0, r1 = e1 - sv1, r2 = e2 - sv2;
      float e20 = sv0 + sigmoid_(gw[0] * r0 + gw[1] * r1 + gw[2] * r2 + gb3[0]) * r0;
      float e21 = sv1 + sigmoid_(gw[3] * r0 + gw[4] * r1 + gw[5] * r2 + gb3[1]) * r1;
      float e22 = sv2 + sigmoid_(gw[6] * r0 + gw[7] * r1 + gw[8] * r2 + gb3[2]) * r2;
      oAp[j] = gelu_(pw[0] * e20 + pw[1] * e21 + pw[2] * e22 + pb3[0]);
      oBp[j] = gelu_(pw[3] * e20 + pw[4] * e21 + pw[5] * e22 + pb3[1]);
      oCp[j] = gelu_(pw[6] * e20 + pw[7] * e21 + pw[8] * e22 + pb3[2]);
    }
    *(float4*)(outB + e) = oA;
    *(float4*)(outB + PLANE + e) = oB;
    *(float4*)(outB + 2 * PLANE + e) = oC;
  }
}

// ---- fused fallback: R13 kernel verbatim (runs if ws too small) ----------------
__global__ __launch_bounds__(256, 6)
void fused_kernel(const float* __restrict__ spec,
                  const float* __restrict__ ws,
                  const float* __restrict__ align_w,
                  const float* __restrict__ align_b,
                  const float* __restrict__ fc1_w,
                  const float* __restrict__ fc1_b,
                  const float* __restrict__ fc2_w,
                  const float* __restrict__ fc2_b,
                  const float* __restrict__ band_gain,
                  const float* __restrict__ gate_w,
                  const float* __restrict__ gate_b,
                  float* __restrict__ out)
{
  __shared__ unsigned sPoolU[POOLU];
  __shared__ unsigned sWu[WTOTU];
  __shared__ float sBand[TTF][109];
  __shared__ float sAw[54], sAb[18], sF1[108], sF1b[6], sF2[108], sF2b[18],
                   sBg[6], sGw[9], sGb[3], sPw[9], sPb[3];

  const int tid = threadIdx.x;
  const int b   = blockIdx.y;
  const float* specB = spec + (size_t)b * C_ * PLANE;
  float* outBase = out + (size_t)b * C_ * PLANE;
  const unsigned* wsU = (const unsigned*)ws;

  for (int k = tid; k < WTOTU; k += 256) sWu[k] = wsU[k];
  if (tid < 54)  sAw[tid]  = align_w[tid];
  if (tid < 18)  sAb[tid]  = align_b[tid];
  if (tid < 108) sF1[tid]  = fc1_w[tid];
  if (tid < 6)   sF1b[tid] = fc1_b[tid];
  if (tid < 108) sF2[tid]  = fc2_w[tid];
  if (tid < 18)  sF2b[tid] = fc2_b[tid];
  if (tid < 6)   sBg[tid]  = band_gain[tid];
  if (tid < 9)   sGw[tid]  = gate_w[tid];
  if (tid < 3)   sGb[tid]  = gate_b[tid];
  if (tid < 9)   sPw[tid]  = ws[WTOTU + tid];
  if (tid < 3)   sPb[tid]  = ws[WTOTU + 9 + tid];

  for (int tile = 0; tile < NTF; ++tile) {
    const int t0 = (blockIdx.x * NTF + tile) * TTF;
    for (int li = tid; li < SPECW; li += 256) {
      int c   = li / (TTF * SPW);
      int rem = li - c * (TTF * SPW);
      int tt  = rem / SPW;
      int w   = rem - tt * SPW;
      const float* gr = specB + (size_t)c * PLANE + (size_t)(t0 + tt) * F_;
      sPoolU[li] = bf16_rne_(gr[2 * w]) | (bf16_rne_(gr[2 * w + 1]) << 16);
    }
    __syncthreads();
    if (tid < 180) {
      const int g  = tid / TTF;
      const int tt = tid - g * TTF;
      const int c  = g / 3;
      const int np = g - c * 3;
      const int n0 = 2 * np;
      const unsigned* srow = &sPoolU[(c * TTF + tt) * SPW];
      const unsigned* w0 = &sWu[(c * 6 + n0) * WROW];
      const unsigned* w1 = w0 + WROW;
      #pragma unroll
      for (int i = 0; i < NB_; ++i) {
        float a0 = 0.0f, a1 = 0.0f;
        #pragma unroll
        for (int e = 0; e < WCNT[i]; ++e) {
          unsigned su = srow[WSTART[i] + e];
          float s0 = bl_(su), s1 = bh_(su);
          unsigned u0 = w0[WOFF[i] + e], u1 = w1[WOFF[i] + e];
          a0 += s0 * bl_(u0); a0 += s1 * bh_(u0);
          a1 += s0 * bl_(u1); a1 += s1 * bh_(u1);
        }
        sBand[tt][(i * 3 + c) * 6 + n0]     = a0;
        sBand[tt][(i * 3 + c) * 6 + n0 + 1] = a1;
      }
    }
    __syncthreads();
    if (tid < 6 * TTF) {
      int n  = tid / TTF;
      int tt = tid - n * TTF;
      float al[18];
      #pragma unroll
      for (int i = 0; i < 6; ++i) {
        float f0 = sBand[tt][(i * 3 + 0) * 6 + n];
        float f1 = sBand[tt][(i * 3 + 1) * 6 + n];
        float f2 = sBand[tt][(i * 3 + 2) * 6 + n];
        #pragma unroll
        for (int d = 0; d < 3; ++d)
          al[i * 3 + d] = sAw[i * 9 + d * 3 + 0] * f0 + sAw[i * 9 + d * 3 + 1] * f1 +
                          sAw[i * 9 + d * 3 + 2] * f2 + sAb[i * 3 + d];
      }
      float h[6];
      #pragma unroll
      for (int o = 0; o < 6; ++o) {
        float acc = sF1b[o];
        #pragma unroll
        for (int k = 0; k < 18; ++k) acc += sF1[o * 18 + k] * al[k];
        h[o] = gelu_(acc);
      }
      float at[18];
      #pragma unroll
      for (int k = 0; k < 18; ++k) {
        float acc = sF2b[k];
        #pragma unroll
        for (int o = 0; o < 6; ++o) acc += sF2[k * 6 + o] * h[o];
        at[k] = acc;
      }
      #pragma unroll
      for (int c = 0; c < 3; ++c) {
        float m = at[c];
        #pragma unroll
        for (int i = 1; i < 6; ++i) m = fmaxf(m, at[i * 3 + c]);
        float e[6], ssum = 0.0f;
        #pragma unroll
        for (int i = 0; i < 6; ++i) { e[i] = __expf(at[i * 3 + c] - m); ssum += e[i]; }
        float inv = 1.0f / ssum;
        #pragma unroll
        for (int i = 0; i < 6; ++i)
          sBand[tt][(i * 3 + c) * 6 + n] = al[i * 3 + c] * (e[i] * inv) * sBg[i];
      }
    }
    __syncthreads();
    if (tid < C_ * TTF) {
      const int c  = tid / TTF;
      const int tt = tid - c * TTF;
      float bnd[36];
      #pragma unroll
      for (int i = 0; i < 6; ++i)
        #pragma unroll
        for (int n = 0; n < 6; ++n)
          bnd[i * 6 + n] = sBand[tt][(i * 3 + c) * 6 + n];
      unsigned* rowU = &sPoolU[c * EPL + tt * ERS];
      float pend = 0.0f, carry = 0.0f;
      #pragma unroll
      for (int i = 0; i < NB_; ++i) {
        #pragma unroll
        for (int j = 0; j < BNB[i]; ++j) {
          const int f = BS[i] + j;
          float src = ((float)j + 0.5f) * 6.0f / (float)BNB[i] - 0.5f;
          src = src > 0.0f ? src : 0.0f;
          int   x0 = (int)src;
          int   x1 = (x0 < 5) ? x0 + 1 : 5;
          float wl = src - (float)x0;
          float v  = bnd[i * 6 + x0] * (1.0f - wl) + bnd[i * 6 + x1] * wl;
          if (j == 0) v += carry;
          if (i < NB_ - 1 && j == BNB[i] - 1) carry = v;
          else {
            if (f & 1) rowU[f >> 1] = bf16_rne_(pend) | (bf16_rne_(v) << 16);
            else       pend = v;
          }
        }
      }
      rowU[38] = bf16_rne_(pend);
      #pragma unroll
      for (int w = 39; w < ERS; ++w) rowU[w] = 0u;
    }
    __syncthreads();
    float gw[9], pw[9], gb3[3], pb3[3];
    #pragma unroll
    for (int k = 0; k < 9; ++k) { gw[k] = sGw[k]; pw[k] = sPw[k]; }
    #pragma unroll
    for (int k = 0; k < 3; ++k) { gb3[k] = sGb[k]; pb3[k] = sPb[k]; }
    const float* sp0 = specB + (size_t)t0 * F_;
    float* outB = outBase + (size_t)t0 * F_;
    for (int e4 = tid; e4 < (TTF * F_) / 4; e4 += 256) {
      const int e = e4 * 4;
      const float4 sA = *(const float4*)(sp0 + e);
      const float4 sB = *(const float4*)(sp0 + PLANE + e);
      const float4 sC = *(const float4*)(sp0 + 2 * PLANE + e);
      float4 oA, oB, oC;
      const float* sAp = (const float*)&sA; const float* sBp = (const float*)&sB;
      const float* sCp = (const float*)&sC;
      float* oAp = (float*)&oA; float* oBp = (float*)&oB; float* oCp = (float*)&oC;
      #pragma unroll
      for (int j = 0; j < 4; ++j) {
        const int idx = e + j;
        const int tt  = idx / F_;
        const int f   = idx - tt * F_;
        const int wd  = tt * ERS + (f >> 1);
        const unsigned ua = sPoolU[0 * EPL + wd];
        const unsigned ub = sPoolU[1 * EPL + wd];
        const unsigned uc = sPoolU[2 * EPL + wd];
        const bool hi = (f & 1);
        float e0 = hi ? bh_(ua) : bl_(ua);
        float e1 = hi ? bh_(ub) : bl_(ub);
        float e2 = hi ? bh_(uc) : bl_(uc);
        float sv0 = sAp[j], sv1 = sBp[j], sv2 = sCp[j];
        float r0 = e0 - sv0, r1 = e1 - sv1, r2 = e2 - sv2;
        float e20 = sv0 + sigmoid_(gw[0] * r0 + gw[1] * r1 + gw[2] * r2 + gb3[0]) * r0;
        float e21 = sv1 + sigmoid_(gw[3] * r0 + gw[4] * r1 + gw[5] * r2 + gb3[1]) * r1;
        float e22 = sv2 + sigmoid_(gw[6] * r0 + gw[7] * r1 + gw[8] * r2 + gb3[2]) * r2;
        oAp[j] = gelu_(pw[0] * e20 + pw[1] * e21 + pw[2] * e22 + pb3[0]);
        oBp[j] = gelu_(pw[3] * e20 + pw[4] * e21 + pw[5] * e22 + pb3[1]);
        oCp[j] = gelu_(pw[6] * e20 + pw[7] * e21 + pw[8] * e22 + pb3[2]);
      }
      *(float4*)(outB + e) = oA;
      *(float4*)(outB + PLANE + e) = oB;
      *(float4*)(outB + 2 * PLANE + e) = oC;
    }
    __syncthreads();
  }
}

} // namespace

extern "C" void kernel_launch(void* const* d_in, const int* in_sizes, int n_in,
                              void* d_out, int out_size, void* d_ws, size_t ws_size,
                              hipStream_t stream) {
  (void)n_in; (void)out_size;
  const int B = in_sizes[0] / (C_ * T_ * F_);   // 64
  float* ws = (float*)d_ws;
  prep_kernel<<<1, 256, 0, stream>>>(
      (const float*)d_in[1],  (const float*)d_in[2],  (const float*)d_in[3],
      (const float*)d_in[13], (const float*)d_in[14], (const float*)d_in[15],
      (const float*)d_in[16], (const float*)d_in[17], (const float*)d_in[18], ws);

  const size_t needed = ((size_t)BANDOFF + (size_t)B * T_ * BROW) * 4;
  if (ws_size >= needed) {
    unsigned* band = (unsigned*)ws + BANDOFF;
    dim3 g1((T_ + TT1 - 1) / TT1, B);           // (94, 64)
    band_kernel<<<g1, 192, 0, stream>>>(
        (const float*)d_in[0], ws,
        (const float*)d_in[4], (const float*)d_in[5],
        (const float*)d_in[6], (const float*)d_in[7], (const float*)d_in[8],
        (const float*)d_in[9], (const float*)d_in[10], band);
    dim3 g2(T_ / TT2, B);                       // (150, 64)
    out_kernel<<<g2, 256, 0, stream>>>(
        (const float*)d_in[0], ws, band,
        (const float*)d_in[11], (const float*)d_in[12], (float*)d_out);
  } else {
    dim3 gf(T_ / (TTF * NTF), B);               // (50, 64)
    fused_kernel<<<gf, 256, 0, stream>>>(
        (const float*)d_in[0], ws,
        (const float*)d_in[4],  (const float*)d_in[5],
        (const float*)d_in[6],  (const float*)d_in[7],  (const float*)d_in[8],
        (const float*)d_in[9],  (const float*)d_in[10], (const float*)d_in[11],
        (const float*)d_in[12], (float*)d_out);
  }
}

// Round 18
// 234.745 us; speedup vs baseline: 1.5192x; 1.2154x over previous
//
#include <hip/hip_runtime.h>
#include <math.h>

namespace {

constexpr int C_ = 3, T_ = 3000, F_ = 103, NB_ = 6;
constexpr int TT = 20;                       // t-steps per tile
constexpr int NT = 3;                        // tiles per block; 3000/(20*3)=50 chunks
constexpr int BS[NB_]  = {1, 10, 20, 30, 40, 61};
constexpr int BNB[NB_] = {10, 11, 11, 11, 22, 16};
// packed-on-global-parity weight/spec word geometry
constexpr int WSTART[NB_] = {0, 5, 10, 15, 20, 30};  // BS[i]>>1
constexpr int WCNT[NB_]   = {6, 6, 6, 6, 11, 9};     // words covering each band
constexpr int WOFF[NB_]   = {0, 6, 12, 18, 24, 35};  // cumsum WCNT; row = 44
constexpr int WROW = 44;
constexpr int WTOTU = 18 * WROW;             // 792 packed u32 weights
constexpr int SPW = 39;                      // packed spec words per (c,tt) row (f 0..77)
constexpr int SPECW = C_ * TT * SPW;         // 2340
constexpr int ERS = 52;                      // enh row stride (u32), f 0..103
constexpr int EPL = TT * ERS;                // 1040 per c plane
constexpr int POOLU = 3 * EPL;               // 3120 u32 >= SPECW (aliased)
constexpr int PLANE = T_ * F_;               // 309000

__device__ __forceinline__ float softplus_(float x) {
  return fmaxf(x, 0.0f) + log1pf(expf(-fabsf(x)));
}
__device__ __forceinline__ float sigmoid_(float z) {
  return 1.0f / (1.0f + __expf(-z));
}
__device__ __forceinline__ float gelu_(float x) {
  return x * sigmoid_(1.595769122f * x * (1.0f + 0.044715f * x * x));
}
__device__ __forceinline__ unsigned bf16_rne_(float x) {
  unsigned b = __float_as_uint(x);
  b += 0x7FFFu + ((b >> 16) & 1u);
  return b >> 16;
}
__device__ __forceinline__ float bl_(unsigned u) { return __uint_as_float(u << 16); }
__device__ __forceinline__ float bh_(unsigned u) { return __uint_as_float(u & 0xffff0000u); }

// ---- pre-kernel: global-parity packed bf16 gaussian bank + folded proj/BN -----
// u32 [0..791]: weight pairs; word e of band i covers f = 2*(WSTART+e), 2*(..)+1
// f32 [792..800]: projBN w ; [801..803]: projBN b
__global__ __launch_bounds__(128)
void prep_kernel(const float* __restrict__ centers,
                 const float* __restrict__ widths,
                 const float* __restrict__ gains,
                 const float* __restrict__ proj_w,
                 const float* __restrict__ proj_b,
                 const float* __restrict__ bn_gamma,
                 const float* __restrict__ bn_beta,
                 const float* __restrict__ bn_mean,
                 const float* __restrict__ bn_var,
                 float* __restrict__ ws)
{
  unsigned* wsU = (unsigned*)ws;
  const int q = threadIdx.x;
  if (q < 108) {
    int i = q / 18;
    int p = q - i * 18;                       // c*6+n
    int s = BS[i], nb = BNB[i];
    float mu = softplus_(centers[q]) + (float)s;
    mu = fminf(fmaxf(mu, (float)s), (float)(s + nb - 1));
    float sd = softplus_(widths[q]) + 0.001f;
    sd = fminf(fmaxf(sd, 0.5f), 2.0f * (float)nb / 6.0f);
    float sum = 0.0f;
    for (int f = 0; f < nb; ++f) {
      float d = ((float)f - mu) / sd;
      sum += __expf(-0.5f * d * d);
    }
    float sc = gains[q] / (sum + 1e-6f);
    float wtmp[22];
    for (int f = 0; f < nb; ++f) {
      float d = ((float)f - mu) / sd;
      wtmp[f] = sc * __expf(-0.5f * d * d);
    }
    for (int e = 0; e < WCNT[i]; ++e) {
      int flo = 2 * (WSTART[i] + e) - s;      // band-local index of lo slot
      int fhi = flo + 1;
      unsigned lo = (flo >= 0 && flo < nb) ? bf16_rne_(wtmp[flo]) : 0u;
      unsigned hi = (fhi >= 0 && fhi < nb) ? bf16_rne_(wtmp[fhi]) : 0u;
      wsU[p * WROW + WOFF[i] + e] = lo | (hi << 16);
    }
  } else if (q < 117) {
    int k = q - 108, d = k / 3;
    float sc = bn_gamma[d] / sqrtf(bn_var[d] + 1e-5f);
    ws[WTOTU + k] = proj_w[k] * sc;
  } else if (q < 120) {
    int d = q - 117;
    float sc = bn_gamma[d] / sqrtf(bn_var[d] + 1e-5f);
    ws[WTOTU + 9 + d] = (proj_b[d] - bn_mean[d]) * sc + bn_beta[d];
  }
}

// ---- main kernel: R11 structure, all big LDS arrays packed bf16 ---------------
__global__ __launch_bounds__(256, 6)
void sleepband_kernel(const float* __restrict__ spec,
                      const float* __restrict__ ws,
                      const float* __restrict__ align_w,
                      const float* __restrict__ align_b,
                      const float* __restrict__ fc1_w,
                      const float* __restrict__ fc1_b,
                      const float* __restrict__ fc2_w,
                      const float* __restrict__ fc2_b,
                      const float* __restrict__ band_gain,
                      const float* __restrict__ gate_w,
                      const float* __restrict__ gate_b,
                      float* __restrict__ out)
{
  // pool (u32): [stage/A] packed spec [c][tt][39]  ||  [B2/final] packed enh [c][tt][52]
  __shared__ unsigned sPoolU[POOLU];
  __shared__ unsigned sWu[WTOTU];        // packed bf16 weight pairs, persistent
  __shared__ float sBand[TT][109];       // odd stride -> conflict-free
  __shared__ float sAw[54], sAb[18], sF1[108], sF1b[6], sF2[108], sF2b[18],
                   sBg[6], sGw[9], sGb[3], sPw[9], sPb[3];

  const int tid = threadIdx.x;
  const int b   = blockIdx.y;
  const float* specB = spec + (size_t)b * C_ * PLANE;
  float* outBase = out + (size_t)b * C_ * PLANE;
  const unsigned* wsU = (const unsigned*)ws;

  // ---- one-time prologue: params + packed gaussian weights ----
  for (int k = tid; k < WTOTU; k += 256) sWu[k] = wsU[k];
  if (tid < 54)  sAw[tid]  = align_w[tid];
  if (tid < 18)  sAb[tid]  = align_b[tid];
  if (tid < 108) sF1[tid]  = fc1_w[tid];
  if (tid < 6)   sF1b[tid] = fc1_b[tid];
  if (tid < 108) sF2[tid]  = fc2_w[tid];
  if (tid < 18)  sF2b[tid] = fc2_b[tid];
  if (tid < 6)   sBg[tid]  = band_gain[tid];
  if (tid < 9)   sGw[tid]  = gate_w[tid];
  if (tid < 3)   sGb[tid]  = gate_b[tid];
  if (tid < 9)   sPw[tid]  = ws[WTOTU + tid];
  if (tid < 3)   sPb[tid]  = ws[WTOTU + 9 + tid];

  for (int tile = 0; tile < NT; ++tile) {
    const int t0 = (blockIdx.x * NT + tile) * TT;

    // ---- stage spec as packed bf16 pairs (f 0..77) ----
    for (int li = tid; li < SPECW; li += 256) {
      int c   = li / (TT * SPW);
      int rem = li - c * (TT * SPW);
      int tt  = rem / SPW;
      int w   = rem - tt * SPW;
      const float* gr = specB + (size_t)c * PLANE + (size_t)(t0 + tt) * F_;
      unsigned lo = bf16_rne_(gr[2 * w]);
      unsigned hi = bf16_rne_(gr[2 * w + 1]);
      sPoolU[li] = lo | (hi << 16);
    }
    __syncthreads();

    // ---- Phase A: filt via packed spec x packed weights, n-pair tasks (180) ----
    if (tid < 180) {
      const int g  = tid / TT;             // c*3 + np
      const int tt = tid - g * TT;
      const int c  = g / 3;
      const int np = g - c * 3;
      const int n0 = 2 * np;
      const unsigned* srow = &sPoolU[(c * TT + tt) * SPW];
      const unsigned* w0 = &sWu[(c * 6 + n0) * WROW];
      const unsigned* w1 = w0 + WROW;
      #pragma unroll
      for (int i = 0; i < NB_; ++i) {
        float a0 = 0.0f, a1 = 0.0f;
        #pragma unroll
        for (int e = 0; e < WCNT[i]; ++e) {
          unsigned su = srow[WSTART[i] + e];
          float s0 = bl_(su), s1 = bh_(su);
          unsigned u0 = w0[WOFF[i] + e], u1 = w1[WOFF[i] + e];
          a0 += s0 * bl_(u0); a0 += s1 * bh_(u0);
          a1 += s0 * bl_(u1); a1 += s1 * bh_(u1);
        }
        sBand[tt][(i * 3 + c) * 6 + n0]     = a0;
        sBand[tt][(i * 3 + c) * 6 + n0 + 1] = a1;
      }
    }
    __syncthreads();

    // ---- Phase B: align + MLP + softmax + scale (120 tasks) ----
    if (tid < 6 * TT) {
      int n  = tid / TT;
      int tt = tid - n * TT;
      float al[18];
      #pragma unroll
      for (int i = 0; i < 6; ++i) {
        float f0 = sBand[tt][(i * 3 + 0) * 6 + n];
        float f1 = sBand[tt][(i * 3 + 1) * 6 + n];
        float f2 = sBand[tt][(i * 3 + 2) * 6 + n];
        #pragma unroll
        for (int d = 0; d < 3; ++d)
          al[i * 3 + d] = sAw[i * 9 + d * 3 + 0] * f0 + sAw[i * 9 + d * 3 + 1] * f1 +
                          sAw[i * 9 + d * 3 + 2] * f2 + sAb[i * 3 + d];
      }
      float h[6];
      #pragma unroll
      for (int o = 0; o < 6; ++o) {
        float acc = sF1b[o];
        #pragma unroll
        for (int k = 0; k < 18; ++k) acc += sF1[o * 18 + k] * al[k];
        h[o] = gelu_(acc);
      }
      float at[18];
      #pragma unroll
      for (int k = 0; k < 18; ++k) {
        float acc = sF2b[k];
        #pragma unroll
        for (int o = 0; o < 6; ++o) acc += sF2[k * 6 + o] * h[o];
        at[k] = acc;
      }
      #pragma unroll
      for (int c = 0; c < 3; ++c) {
        float m = at[c];
        #pragma unroll
        for (int i = 1; i < 6; ++i) m = fmaxf(m, at[i * 3 + c]);
        float e[6], ssum = 0.0f;
        #pragma unroll
        for (int i = 0; i < 6; ++i) { e[i] = __expf(at[i * 3 + c] - m); ssum += e[i]; }
        float inv = 1.0f / ssum;
        #pragma unroll
        for (int i = 0; i < 6; ++i)
          sBand[tt][(i * 3 + c) * 6 + n] = al[i * 3 + c] * (e[i] * inv) * sBg[i];
      }
    }
    __syncthreads();

    // ---- Phase B2: upsample -> packed bf16 enh (ascending f, pair-emit) ----
    if (tid < C_ * TT) {
      const int c  = tid / TT;
      const int tt = tid - c * TT;
      float bnd[36];
      #pragma unroll
      for (int i = 0; i < 6; ++i)
        #pragma unroll
        for (int n = 0; n < 6; ++n)
          bnd[i * 6 + n] = sBand[tt][(i * 3 + c) * 6 + n];
      unsigned* rowU = &sPoolU[c * EPL + tt * ERS];
      float pend = 0.0f;                     // f=0 value is 0 (even -> pending)
      float carry = 0.0f;
      #pragma unroll
      for (int i = 0; i < NB_; ++i) {
        #pragma unroll
        for (int j = 0; j < BNB[i]; ++j) {
          const int f = BS[i] + j;
          float src = ((float)j + 0.5f) * 6.0f / (float)BNB[i] - 0.5f;
          src = src > 0.0f ? src : 0.0f;
          int   x0 = (int)src;
          int   x1 = (x0 < 5) ? x0 + 1 : 5;
          float wl = src - (float)x0;
          float v  = bnd[i * 6 + x0] * (1.0f - wl) + bnd[i * 6 + x1] * wl;
          if (j == 0) v += carry;
          if (i < NB_ - 1 && j == BNB[i] - 1) {
            carry = v;                       // overlap bin: deferred to next band
          } else {
            if (f & 1) rowU[f >> 1] = bf16_rne_(pend) | (bf16_rne_(v) << 16);
            else       pend = v;
          }
        }
      }
      rowU[38] = bf16_rne_(pend);            // f=76 (lo), f=77 zero (hi)
      #pragma unroll
      for (int w = 39; w < ERS; ++w) rowU[w] = 0u;
    }
    __syncthreads();

    // ---- Final: flat float4 gate + folded proj + gelu (enh from packed LDS) ----
    float gw[9], pw[9], gb3[3], pb3[3];
    #pragma unroll
    for (int k = 0; k < 9; ++k) { gw[k] = sGw[k]; pw[k] = sPw[k]; }
    #pragma unroll
    for (int k = 0; k < 3; ++k) { gb3[k] = sGb[k]; pb3[k] = sPb[k]; }

    const float* sp0 = specB + (size_t)t0 * F_;
    float* outB = outBase + (size_t)t0 * F_;
    for (int e4 = tid; e4 < (TT * F_) / 4; e4 += 256) {
      const int e = e4 * 4;
      const float4 sA = *(const float4*)(sp0 + e);
      const float4 sB = *(const float4*)(sp0 + PLANE + e);
      const float4 sC = *(const float4*)(sp0 + 2 * PLANE + e);
      float4 oA, oB, oC;
      const float* sAp = (const float*)&sA; const float* sBp = (const float*)&sB;
      const float* sCp = (const float*)&sC;
      float* oAp = (float*)&oA; float* oBp = (float*)&oB; float* oCp = (float*)&oC;
      #pragma unroll
      for (int j = 0; j < 4; ++j) {
        const int idx = e + j;
        const int tt  = idx / F_;            // const-div -> magic mul
        const int f   = idx - tt * F_;
        const int wd  = tt * ERS + (f >> 1);
        const unsigned ua = sPoolU[0 * EPL + wd];
        const unsigned ub = sPoolU[1 * EPL + wd];
        const unsigned uc = sPoolU[2 * EPL + wd];
        const bool hi = (f & 1);
        float e0 = hi ? bh_(ua) : bl_(ua);
        float e1 = hi ? bh_(ub) : bl_(ub);
        float e2 = hi ? bh_(uc) : bl_(uc);
        float sv0 = sAp[j], sv1 = sBp[j], sv2 = sCp[j];
        float r0 = e0 - sv0, r1 = e1 - sv1, r2 = e2 - sv2;
        float e20 = sv0 + sigmoid_(gw[0] * r0 + gw[1] * r1 + gw[2] * r2 + gb3[0]) * r0;
        float e21 = sv1 + sigmoid_(gw[3] * r0 + gw[4] * r1 + gw[5] * r2 + gb3[1]) * r1;
        float e22 = sv2 + sigmoid_(gw[6] * r0 + gw[7] * r1 + gw[8] * r2 + gb3[2]) * r2;
        float y0 = pw[0] * e20 + pw[1] * e21 + pw[2] * e22 + pb3[0];
        float y1 = pw[3] * e20 + pw[4] * e21 + pw[5] * e22 + pb3[1];
        float y2 = pw[6] * e20 + pw[7] * e21 + pw[8] * e22 + pb3[2];
        oAp[j] = gelu_(y0); oBp[j] = gelu_(y1); oCp[j] = gelu_(y2);
      }
      *(float4*)(outB + e) = oA;
      *(float4*)(outB + PLANE + e) = oB;
      *(float4*)(outB + 2 * PLANE + e) = oC;
    }
    __syncthreads();   // protect sPoolU (enh) before next tile's staging
  }
}

} // namespace

extern "C" void kernel_launch(void* const* d_in, const int* in_sizes, int n_in,
                              void* d_out, int out_size, void* d_ws, size_t ws_size,
                              hipStream_t stream) {
  (void)n_in; (void)out_size; (void)ws_size;
  const int B = in_sizes[0] / (C_ * T_ * F_);   // 64
  float* ws = (float*)d_ws;                     // 792 u32 + 12 f32
  prep_kernel<<<1, 128, 0, stream>>>(
      (const float*)d_in[1],  (const float*)d_in[2],  (const float*)d_in[3],
      (const float*)d_in[13], (const float*)d_in[14], (const float*)d_in[15],
      (const float*)d_in[16], (const float*)d_in[17], (const float*)d_in[18], ws);
  dim3 grid(T_ / (TT * NT), B);                 // (50, 64)
  sleepband_kernel<<<grid, 256, 0, stream>>>(
      (const float*)d_in[0],  ws,
      (const float*)d_in[4],  (const float*)d_in[5],
      (const float*)d_in[6],  (const float*)d_in[7],  (const float*)d_in[8],
      (const float*)d_in[9],  (const float*)d_in[10], (const float*)d_in[11],
      (const float*)d_in[12], (float*)d_out);
}